// Round 16
// baseline (193.989 us; speedup 1.0000x reference)
//
#include <hip/hip_runtime.h>
#include <stdint.h>

// PETNNCell collapse (proven analytically):
//   T_t == 0, m == 1;  C_new = I_t + Z_c;  h = sigmoid(X @ W_h[:, :512]^T + b_h)
//   S_new = sigmoid((1 - Z_w)*S_prev + Z_w*h + X)
//
// R16: ZERO-LDS GEMM. All ten staged variants (R5-R15) plateaued at
// 21-27% MfmaUtil; the invariant was the staging pipeline (DMA + LDS
// round-trip + block-wide barrier/vmcnt each tile). Here MFMA fragments
// load DIRECTLY from global: per row one K=64 tile = exactly one 128B
// line (fully consumed); waves sharing wm/wn read identical addresses ->
// L1 dedup keeps per-CU L2 traffic ~64KB/tile. No barriers (one bare
// s_barrier/tile for wave convergence), no vmcnt choreography, no LDS.
// Compiler owns the schedule. Keeps R14's 4-output merge (intensity),
// XCD swizzle, bf16 prepass, fused epilogue.

#define BROWS 16384
#define DDIM  512

typedef __bf16 bf16x8 __attribute__((ext_vector_type(8)));
typedef __bf16 bf16x4 __attribute__((ext_vector_type(4)));
typedef float  f32x4  __attribute__((ext_vector_type(4)));

__device__ __forceinline__ float sigf(float x) { return 1.0f / (1.0f + __expf(-x)); }

__device__ __forceinline__ bf16x4 cvt4(f32x4 v) {
    bf16x4 r;
    r[0] = (__bf16)v[0]; r[1] = (__bf16)v[1];
    r[2] = (__bf16)v[2]; r[3] = (__bf16)v[3];
    return r;
}

__device__ __forceinline__ void glds16(const __bf16* g, __bf16* l) {
    __builtin_amdgcn_global_load_lds(
        (const __attribute__((address_space(1))) void*)g,
        (__attribute__((address_space(3))) void*)l, 16, 0, 0);
}

// ===================== prepass: X, S, weights -> bf16 (+ T_t zero) ==========
// ws elems: [0) Xb 8388608 | [8388608) Sb 8388608 | [16777216) weights:
//   +0 Wzc 512x1024 | +524288 Wzw 512x1024 | +1048576 Wit 512x512
//   | +1310720 Wh' 512x512 (cols 0..511). Total 18350080 elems = 36.7 MB.
__global__ __launch_bounds__(256)
void petnn_cvt(const float* __restrict__ X,   const float* __restrict__ S,
               const float* __restrict__ Wzc, const float* __restrict__ Wzw,
               const float* __restrict__ Wit, const float* __restrict__ Wh,
               __bf16* __restrict__ ws, float* __restrict__ outT)
{
    const int i = blockIdx.x * 256 + threadIdx.x;   // f32x4 chunk
    if (i >= 4587520) {                             // T_t == 0 exactly
        const int k = i - 4587520;                  // 0..4095
        *(f32x4*)(outT + (size_t)k * 4) = f32x4{0.f, 0.f, 0.f, 0.f};
        return;
    }
    const float* src; size_t dst;
    if (i < 2097152)      { src = X + (size_t)i * 4; dst = (size_t)i * 4; }
    else if (i < 4194304) { const int j = i - 2097152;
                            src = S + (size_t)j * 4; dst = 8388608 + (size_t)j * 4; }
    else {
        const int j = i - 4194304;                  // 0..393215 (weights)
        if (j < 131072)      { src = Wzc + (size_t)j * 4;
                               dst = 16777216 + (size_t)j * 4; }
        else if (j < 262144) { const int jj = j - 131072;
                               src = Wzw + (size_t)jj * 4;
                               dst = 16777216 + 524288 + (size_t)jj * 4; }
        else if (j < 327680) { const int jj = j - 262144;
                               src = Wit + (size_t)jj * 4;
                               dst = 16777216 + 1048576 + (size_t)jj * 4; }
        else                 { const int jj = j - 327680;   // Wh cols 0..511
                               src = Wh + (size_t)(jj >> 7) * 1024 + (jj & 127) * 4;
                               dst = 16777216 + 1310720 + (size_t)jj * 4; }
    }
    *(bf16x4*)(ws + dst) = cvt4(*(const f32x4*)src);
}

// ===================== main: zero-LDS direct-fragment GEMM ==================
// BM=256 x BN=64, 4 outputs (Zc,Zw: K=1024, tiles 0..15; It,h: K=512,
// tiles 0..7). 512 thr = 8 waves 4(M) x 2(N); wave tile 64x32 x 4 outs;
// acc 128/thread. NO LDS.
__global__ __launch_bounds__(512, 2)
void petnn_fusedD(const __bf16* __restrict__ Xb, const __bf16* __restrict__ Sb,
                  const __bf16* __restrict__ wb,
                  const float* __restrict__ bzc, const float* __restrict__ bzw,
                  const float* __restrict__ bit_, const float* __restrict__ bh,
                  float* __restrict__ out)
{
    const int tid = threadIdx.x;
    const int bid = blockIdx.x;
    // XCD-chunked swizzle (512 wgs, bijective; HW XCD = bid & 7), nblk-minor:
    // per XCD 8 mblk x 8 nblk -> A panels + weights L2/L3-shared per XCD.
    const int orig = (bid & 7) * 64 + (bid >> 3);
    const int nblk = orig & 7;
    const int mblk = orig >> 3;            // 0..63

    const int lane = tid & 63, wid = tid >> 6;
    const int wm = wid >> 1;               // 0..3 (64-row slice of 256)
    const int wn = wid & 1;                // 0..1 (32-col slice of 64)
    const int l15 = lane & 15;
    const int kc  = lane >> 4;             // k-chunk 0..3 (8 bf16 each)

    const int arow0 = mblk * 256;
    const int ncol0 = nblk * 64;

    // ---- per-lane fragment base pointers ----
    // A frag (16x16x32): row = arow0 + wm*64 + mf*16 + l15; elems k = kk*32 + kc*8 ..+7
    const size_t arow = (size_t)(arow0 + wm * 64 + l15);
    const __bf16* pXA = Xb + arow * 512 + kc * 8;
    const __bf16* pSA = Sb + arow * 512 + kc * 8;
    // B frag: col = ncol0 + wn*32 + nf*16 + l15
    const size_t bcol = (size_t)(ncol0 + wn * 32 + l15);
    const __bf16* pZc = wb +       0 + bcol * 1024 + kc * 8;   // K=1024
    const __bf16* pZw = wb +  524288 + bcol * 1024 + kc * 8;   // K=1024
    const __bf16* pIt = wb + 1048576 + bcol * 512  + kc * 8;   // K=512
    const __bf16* pH  = wb + 1310720 + bcol * 512  + kc * 8;   // K=512

    f32x4 acc[4][4][2] = {};    // [out][mf][nf]

    // ---- K loop: tiles 0..7 full (X part, 4 outs), 8..15 tail (S, Zc/Zw) ----
#define BODY(AP, KTOFF, PZC_OFF, NOUT)                                        \
    {                                                                         \
        bf16x8 a_[2][4];                                                      \
        _Pragma("unroll")                                                     \
        for (int kk = 0; kk < 2; ++kk)                                        \
            _Pragma("unroll")                                                 \
            for (int mf = 0; mf < 4; ++mf)                                    \
                a_[kk][mf] = *(const bf16x8*)((AP) + (size_t)mf * 8192 + (KTOFF) + kk * 32); \
        _Pragma("unroll")                                                     \
        for (int o = 0; o < (NOUT); ++o) {                                    \
            const __bf16* pb_ = (o == 0) ? pZc + (PZC_OFF) :                  \
                                (o == 1) ? pZw + (PZC_OFF) :                  \
                                (o == 2) ? pIt + (KTOFF)   : pH + (KTOFF);    \
            const size_t nstride_ = (o < 2) ? 16384 : 8192;  /* 16 cols x K */ \
            bf16x8 b_[2][2];                                                  \
            _Pragma("unroll")                                                 \
            for (int kk = 0; kk < 2; ++kk)                                    \
                _Pragma("unroll")                                             \
                for (int nf = 0; nf < 2; ++nf)                                \
                    b_[kk][nf] = *(const bf16x8*)(pb_ + nf * nstride_ + kk * 32); \
            _Pragma("unroll")                                                 \
            for (int kk = 0; kk < 2; ++kk)                                    \
                _Pragma("unroll")                                             \
                for (int nf = 0; nf < 2; ++nf)                                \
                    _Pragma("unroll")                                         \
                    for (int mf = 0; mf < 4; ++mf)                            \
                        acc[o][mf][nf] = __builtin_amdgcn_mfma_f32_16x16x32_bf16( \
                            a_[kk][mf], b_[kk][nf], acc[o][mf][nf], 0, 0, 0); \
        }                                                                     \
    }

    #pragma unroll
    for (int kt = 0; kt < 8; ++kt) {
        __builtin_amdgcn_s_barrier();      // bare sync: keep waves converged
        BODY(pXA, kt * 64, kt * 64, 4)     // for L1 fragment dedup
    }
    #pragma unroll
    for (int kt = 8; kt < 16; ++kt) {
        __builtin_amdgcn_s_barrier();
        BODY(pSA, (kt - 8) * 64, kt * 64, 2)
    }
#undef BODY

    // ---- fused epilogue (bf16 Xb/Sb reads) ----
    // C/D frag layout (m89/m91): col = lane&15, row = (lane>>4)*4 + reg
    const int rowb = arow0 + wm * 64;
    #pragma unroll
    for (int nf = 0; nf < 2; ++nf) {
        const int col = ncol0 + wn * 32 + nf * 16 + l15;
        const float vzc = bzc[col], vzw = bzw[col], vit = bit_[col], vh = bh[col];
        #pragma unroll
        for (int mf = 0; mf < 4; ++mf) {
            #pragma unroll
            for (int j = 0; j < 4; ++j) {
                const int row = rowb + mf * 16 + (lane >> 4) * 4 + j;
                const size_t off = (size_t)row * DDIM + col;
                const float zw = sigf(acc[1][mf][nf][j] + vzw);
                const float hh = sigf(acc[3][mf][nf][j] + vh);
                out[off] = sigf((1.0f - zw) * (float)Sb[off] + zw * hh
                                + (float)Xb[off]);                         // S_new
                out[(size_t)BROWS * DDIM + off] =
                    (acc[0][mf][nf][j] + vzc) + (acc[2][mf][nf][j] + vit); // C_new
            }
        }
    }
}

// ===================== fallback (ws too small): R4 path =====================
__global__ __launch_bounds__(256)
void petnn_cvtw(const float* __restrict__ Wzw, const float* __restrict__ Wh,
                const float* __restrict__ Wzc, const float* __restrict__ Wit,
                __bf16* __restrict__ wb)
{
    const int i = blockIdx.x * 256 + threadIdx.x;
    const float* src; size_t dst;
    if (i < 131072)      { src = Wzw + (size_t)i * 4;  dst = (size_t)i * 4; }
    else if (i < 196608) { const int j = i - 131072;
                           src = Wh + (size_t)(j >> 7) * 1024 + (j & 127) * 4;
                           dst = 524288 + (size_t)j * 4; }
    else if (i < 327680) { const int j = i - 196608;
                           src = Wzc + (size_t)j * 4;  dst = 786432 + (size_t)j * 4; }
    else                 { const int j = i - 327680;
                           src = Wit + (size_t)j * 4;  dst = 1310720 + (size_t)j * 4; }
    *(bf16x4*)(wb + dst) = cvt4(*(const f32x4*)src);
}

__global__ __launch_bounds__(512, 4)
void petnn_fused(const float* __restrict__ X,   const float* __restrict__ S,
                 const __bf16* __restrict__ wb,
                 const float* __restrict__ bzw, const float* __restrict__ bh,
                 const float* __restrict__ bzc, const float* __restrict__ bit_,
                 float* __restrict__ out)
{
    __shared__ __align__(16) __bf16 sA[128 * 64];
    __shared__ __align__(16) __bf16 sB[2 * 2 * 64 * 64];

    const int tid = threadIdx.x;
    const int bid = blockIdx.x;
    const int orig = (bid & 7) * 256 + (bid >> 3);
    const int fam  = orig & 1;
    const int nblk = (orig >> 1) & 7;
    const int mblk = orig >> 4;
    const int lane = tid & 63, wid = tid >> 6;
    const int wm = wid >> 2, wn = wid & 3;
    const int arow0 = mblk * 128, ncol0 = nblk * 64;
    const int srow = tid >> 4, skq = (tid & 15) << 2;
    const int bn = tid >> 3;
    const int bks = ((tid & 7) ^ (bn & 7)) << 3;
    const __bf16* wP = wb + (size_t)fam * 786432 + (size_t)(ncol0 + bn) * 1024 + bks;
    const __bf16* wQ = wb + (size_t)fam * 786432 + 524288 + (size_t)(ncol0 + bn) * 512 + bks;
    __bf16* ldsB = sB + tid * 8;

    f32x4 aP[4] = {}, aQ[4] = {};
    f32x4 ra[4];

    glds16(wP, ldsB);
    glds16(wQ, ldsB + 4096);
    #pragma unroll
    for (int p = 0; p < 4; ++p)
        ra[p] = *(const f32x4*)(X + (size_t)(arow0 + p * 32 + srow) * DDIM + skq);
    glds16(wP + 64, ldsB + 8192);
    glds16(wQ + 64, ldsB + 8192 + 4096);

    for (int kt = 0; kt < 16; ++kt) {
        const bool full = kt < 8;
        #pragma unroll
        for (int p = 0; p < 4; ++p) {
            const int r = p * 32 + srow;
            *(bf16x4*)(sA + r * 64 + (skq ^ ((r & 7) * 8))) = cvt4(ra[p]);
        }
        if (kt + 1 < 16) {
            const float* asrc = (kt + 1 < 8) ? X : S;
            const int kga = ((kt + 1) & 7) * 64 + skq;
            #pragma unroll
            for (int p = 0; p < 4; ++p)
                ra[p] = *(const f32x4*)(asrc + (size_t)(arow0 + p * 32 + srow) * DDIM + kga);
        }
        asm volatile("s_waitcnt lgkmcnt(0)" ::: "memory");
        __builtin_amdgcn_s_barrier();

        const __bf16* bb = sB + (kt & 1) * 8192;
        #pragma unroll
        for (int kk = 0; kk < 2; ++kk) {
            const int kbe = kk * 32 + (lane >> 4) * 8;
            bf16x8 af[4];
            #pragma unroll
            for (int mf = 0; mf < 4; ++mf) {
                const int r = wm * 64 + mf * 16 + (lane & 15);
                af[mf] = *(const bf16x8*)(sA + r * 64 + (kbe ^ ((r & 7) * 8)));
            }
            const int nr = wn * 16 + (lane & 15);
            const int sx = nr * 64 + (kbe ^ ((nr & 7) * 8));
            const bf16x8 bP = *(const bf16x8*)(bb + sx);
            #pragma unroll
            for (int mf = 0; mf < 4; ++mf)
                aP[mf] = __builtin_amdgcn_mfma_f32_16x16x32_bf16(af[mf], bP, aP[mf], 0, 0, 0);
            if (full) {
                const bf16x8 bQ = *(const bf16x8*)(bb + 4096 + sx);
                #pragma unroll
                for (int mf = 0; mf < 4; ++mf)
                    aQ[mf] = __builtin_amdgcn_mfma_f32_16x16x32_bf16(af[mf], bQ, aQ[mf], 0, 0, 0);
            }
        }

        if (kt + 1 < 16) {
            asm volatile("" ::: "memory");
            __builtin_amdgcn_s_barrier();
            asm volatile("" ::: "memory");
            if (kt + 2 < 16) {
                __bf16* bd = sB + (kt & 1) * 8192 + tid * 8;
                glds16(wP + (size_t)(kt + 2) * 64, bd);
                if (kt + 2 < 8) glds16(wQ + (size_t)(kt + 2) * 64, bd + 4096);
            }
        }
    }

    const int col  = ncol0 + wn * 16 + (lane & 15);
    const int rowb = arow0 + wm * 64;
    if (fam == 0) {
        const float vzw = bzw[col], vh = bh[col];
        #pragma unroll
        for (int mf = 0; mf < 4; ++mf) {
            #pragma unroll
            for (int j = 0; j < 4; ++j) {
                const int row = rowb + mf * 16 + ((lane >> 4) << 2) + j;
                const size_t off = (size_t)row * DDIM + col;
                const float zw = sigf(aP[mf][j] + vzw);
                const float hh = sigf(aQ[mf][j] + vh);
                out[off] = sigf((1.0f - zw) * S[off] + zw * hh + X[off]);
            }
        }
    } else {
        const float vzc = bzc[col], vit = bit_[col];
        #pragma unroll
        for (int mf = 0; mf < 4; ++mf) {
            #pragma unroll
            for (int j = 0; j < 4; ++j) {
                const int row = rowb + mf * 16 + ((lane >> 4) << 2) + j;
                const size_t off = (size_t)row * DDIM + col;
                out[(size_t)BROWS * DDIM + off] =
                    (aP[mf][j] + vzc) + (aQ[mf][j] + vit);
            }
        }
    }
}

__global__ void petnn_zeroT(float* __restrict__ t) {
    t[blockIdx.x * 256 + threadIdx.x] = 0.0f;
}

extern "C" void kernel_launch(void* const* d_in, const int* in_sizes, int n_in,
                              void* d_out, int out_size, void* d_ws, size_t ws_size,
                              hipStream_t stream) {
    (void)in_sizes; (void)n_in; (void)out_size;
    const float* X    = (const float*)d_in[0];
    const float* S    = (const float*)d_in[1];
    const float* Wzc  = (const float*)d_in[6];
    const float* bzc  = (const float*)d_in[7];
    const float* Wzw  = (const float*)d_in[8];
    const float* bzw  = (const float*)d_in[9];
    const float* Wit  = (const float*)d_in[10];
    const float* bit_ = (const float*)d_in[11];
    const float* Wh   = (const float*)d_in[14];
    const float* bh   = (const float*)d_in[15];
    float* out = (float*)d_out;

    if (ws_size >= 36700160u) {
        __bf16* ws = (__bf16*)d_ws;
        const __bf16* Xb = ws;
        const __bf16* Sb = ws + 8388608;
        const __bf16* wb = ws + 16777216;
        petnn_cvt<<<dim3(17936), dim3(256), 0, stream>>>(
            X, S, Wzc, Wzw, Wit, Wh, ws, out + 2 * (size_t)BROWS * DDIM);
        petnn_fusedD<<<dim3(512), dim3(512), 0, stream>>>(
            Xb, Sb, wb, bzc, bzw, bit_, bh, out);
    } else {
        __bf16* wb = (__bf16*)d_ws;
        petnn_cvtw<<<dim3(1536), dim3(256), 0, stream>>>(Wzw, Wh, Wzc, Wit, wb);
        petnn_fused<<<dim3(2048), dim3(512), 0, stream>>>(
            X, S, wb, bzw, bh, bzc, bit_, out);
        petnn_zeroT<<<dim3(64), dim3(256), 0, stream>>>(out + 2 * (size_t)BROWS * DDIM);
    }
}

// Round 17
// 94.704 us; speedup vs baseline: 2.0484x; 2.0484x over previous
//
#include <hip/hip_runtime.h>
#include <stdint.h>

// PETNNCell collapse (proven analytically):
//   T_t == 0, m == 1;  C_new = I_t + Z_c;  h = sigmoid(X @ W_h[:, :512]^T + b_h)
//   S_new = sigmoid((1 - Z_w)*S_prev + Z_w*h + X)
//
// R17: break the lockstep-wave serialization (the 76-us plateau's root):
// R15's two waves/SIMD were from the SAME block -> barriers forced both
// into the same phase (read together, MFMA together -> LDS and matrix pipe
// alternate idle; measured 5737 cyc/tile = LDS 2304 + MFMA 2484 + sync).
// Fix: 256-thread blocks = 1 wave/SIMD, 2 blocks/CU (48 KiB LDS) -> the two
// waves sharing a SIMD come from INDEPENDENT blocks with independent
// barriers -> phases drift, reads overlap MFMAs. Wave tile 128x16x4outs
// (reads/MFMA 0.375, same as R15), BK=32, acc 128. 2-bit swizzle for 64-B
// rows: chunk ^= (row>>1)&3 (uniform 8 lanes/16B-phase-slot = conflict-free).

#define BROWS 16384
#define DDIM  512

typedef __bf16 bf16x8 __attribute__((ext_vector_type(8)));
typedef __bf16 bf16x4 __attribute__((ext_vector_type(4)));
typedef float  f32x4  __attribute__((ext_vector_type(4)));

__device__ __forceinline__ float sigf(float x) { return 1.0f / (1.0f + __expf(-x)); }

__device__ __forceinline__ bf16x4 cvt4(f32x4 v) {
    bf16x4 r;
    r[0] = (__bf16)v[0]; r[1] = (__bf16)v[1];
    r[2] = (__bf16)v[2]; r[3] = (__bf16)v[3];
    return r;
}

__device__ __forceinline__ void glds16(const __bf16* g, __bf16* l) {
    __builtin_amdgcn_global_load_lds(
        (const __attribute__((address_space(1))) void*)g,
        (__attribute__((address_space(3))) void*)l, 16, 0, 0);
}

#define BAR   __builtin_amdgcn_s_barrier()
#define VM0   asm volatile("s_waitcnt vmcnt(0)" ::: "memory")
#define MEMF  asm volatile("" ::: "memory")

// ===================== prepass: X, S, weights -> bf16 (+ T_t zero) ==========
// ws elems: [0) Xb 8388608 | [8388608) Sb 8388608 | [16777216) weights:
//   +0 Wzc 512x1024 | +524288 Wzw 512x1024 | +1048576 Wit 512x512
//   | +1310720 Wh' 512x512 (cols 0..511). Total 18350080 elems = 36.7 MB.
__global__ __launch_bounds__(256)
void petnn_cvt(const float* __restrict__ X,   const float* __restrict__ S,
               const float* __restrict__ Wzc, const float* __restrict__ Wzw,
               const float* __restrict__ Wit, const float* __restrict__ Wh,
               __bf16* __restrict__ ws, float* __restrict__ outT)
{
    const int i = blockIdx.x * 256 + threadIdx.x;   // f32x4 chunk
    if (i >= 4587520) {                             // T_t == 0 exactly
        const int k = i - 4587520;                  // 0..4095
        *(f32x4*)(outT + (size_t)k * 4) = f32x4{0.f, 0.f, 0.f, 0.f};
        return;
    }
    const float* src; size_t dst;
    if (i < 2097152)      { src = X + (size_t)i * 4; dst = (size_t)i * 4; }
    else if (i < 4194304) { const int j = i - 2097152;
                            src = S + (size_t)j * 4; dst = 8388608 + (size_t)j * 4; }
    else {
        const int j = i - 4194304;                  // 0..393215 (weights)
        if (j < 131072)      { src = Wzc + (size_t)j * 4;
                               dst = 16777216 + (size_t)j * 4; }
        else if (j < 262144) { const int jj = j - 131072;
                               src = Wzw + (size_t)jj * 4;
                               dst = 16777216 + 524288 + (size_t)jj * 4; }
        else if (j < 327680) { const int jj = j - 262144;
                               src = Wit + (size_t)jj * 4;
                               dst = 16777216 + 1048576 + (size_t)jj * 4; }
        else                 { const int jj = j - 327680;   // Wh cols 0..511
                               src = Wh + (size_t)(jj >> 7) * 1024 + (jj & 127) * 4;
                               dst = 16777216 + 1310720 + (size_t)jj * 4; }
    }
    *(bf16x4*)(ws + dst) = cvt4(*(const f32x4*)src);
}

// ===================== main: 1-wave/SIMD staggered-block GEMM ===============
// BM=128 x BN=64, 4 outputs (Zc,Zw: K=1024, 32 tiles; It,h: K=512, 16 tiles).
// 256 thr = 4 waves (1 per SIMD), each wave: 128 rows x 16 cols x 4 outs;
// acc = 4outs x 8mf = 32 f32x4 = 128 regs. BK=32.
// LDS: 2 slots x (A 8K + B 16K) = 48 KiB -> 2 blocks/CU (independent phases).
__global__ __launch_bounds__(256, 2)
void petnn_fusedE(const __bf16* __restrict__ Xb, const __bf16* __restrict__ Sb,
                  const __bf16* __restrict__ wb,
                  const float* __restrict__ bzc, const float* __restrict__ bzw,
                  const float* __restrict__ bit_, const float* __restrict__ bh,
                  float* __restrict__ out)
{
    __shared__ __align__(16) __bf16 sA[2 * 4096];   // [slot][128r][32k]  16 KiB
    __shared__ __align__(16) __bf16 sB[2 * 8192];   // [slot][4o][64c][32k] 32 KiB

    const int tid = threadIdx.x;
    const int bid = blockIdx.x;
    // XCD-chunked swizzle (1024 wgs, bijective; HW XCD = bid & 7), nblk-minor:
    // per XCD 16 mblk x 8 nblk -> A panel + weights L2-shared per XCD.
    const int orig = (bid & 7) * 128 + (bid >> 3);
    const int nblk = orig & 7;
    const int mblk = orig >> 3;            // 0..127

    const int lane = tid & 63;
    const int wn   = tid >> 6;             // 0..3: 16-col slice of 64
    const int l15  = lane & 15;
    const int kc   = lane >> 4;            // k-chunk 0..3 (8 bf16 each)

    const int arow0 = mblk * 128;
    const int ncol0 = nblk * 64;

    // ---- staging sources (2-bit swizzle in GLOBAL addr; LDS dest linear) ----
    // thread t stages row/col (t>>2), 16B chunk (t&3);
    // source chunk = (t&3) ^ ((row>>1)&3) = (t&3) ^ ((t>>3)&3).
    const int srow = tid >> 2;             // 0..63
    const int swz8 = ((tid & 3) ^ ((tid >> 3) & 3)) * 8;
    const __bf16* pXA = Xb + (size_t)(arow0 + srow) * 512 + swz8;
    const __bf16* pSA = Sb + (size_t)(arow0 + srow) * 512 + swz8;
    const __bf16* pZc = wb +       0 + (size_t)(ncol0 + srow) * 1024 + swz8; // K=1024
    const __bf16* pZw = wb +  524288 + (size_t)(ncol0 + srow) * 1024 + swz8; // K=1024
    const __bf16* pIt = wb + 1048576 + (size_t)(ncol0 + srow) * 512  + swz8; // K=512
    const __bf16* pH  = wb + 1310720 + (size_t)(ncol0 + srow) * 512  + swz8; // K=512

    // ---- fragment read offsets (elems within one slot) ----
    int aoff[8];
    #pragma unroll
    for (int mf = 0; mf < 8; ++mf) {
        const int r = mf * 16 + l15;
        aoff[mf] = r * 32 + ((kc ^ ((r >> 1) & 3)) * 8);
    }
    const int cb   = wn * 16 + l15;
    const int boff = cb * 32 + ((kc ^ ((cb >> 1) & 3)) * 8);

    f32x4 acc[4][8] = {};    // [out][mf]

    // tile T staging: A 2 units + B 4 units (full) / 2 (tail) x 4KB each
#define ISSUE_T(T) { \
        const __bf16* a_ = (((T) < 16) ? pXA : pSA) + ((T) & 15) * 32; \
        __bf16* dA_ = sA + ((T) & 1) * 4096 + tid * 8; \
        glds16(a_,            dA_); \
        glds16(a_ + 64 * 512, dA_ + 2048); \
        __bf16* dB_ = sB + ((T) & 1) * 8192 + tid * 8; \
        glds16(pZc + (T) * 32, dB_); \
        glds16(pZw + (T) * 32, dB_ + 2048); \
        if ((T) < 16) { \
            glds16(pIt + (T) * 32, dB_ + 4096); \
            glds16(pH  + (T) * 32, dB_ + 6144); \
        } }

    // body: 8 A-frag + NOUT B-frag reads, NOUT x 8 MFMA, setprio-wrapped
#define BODY(T, NOUT) { \
        const __bf16* aS_ = sA + ((T) & 1) * 4096; \
        const __bf16* bS_ = sB + ((T) & 1) * 8192; \
        bf16x8 a_[8]; \
        _Pragma("unroll") \
        for (int mf = 0; mf < 8; ++mf) a_[mf] = *(const bf16x8*)(aS_ + aoff[mf]); \
        __builtin_amdgcn_s_setprio(1); \
        _Pragma("unroll") \
        for (int o = 0; o < (NOUT); ++o) { \
            const bf16x8 b_ = *(const bf16x8*)(bS_ + o * 2048 + boff); \
            _Pragma("unroll") \
            for (int mf = 0; mf < 8; ++mf) \
                acc[o][mf] = __builtin_amdgcn_mfma_f32_16x16x32_bf16( \
                    a_[mf], b_, acc[o][mf], 0, 0, 0); \
        } \
        __builtin_amdgcn_s_setprio(0); }

    // ---- pipeline: depth-1 prefetch, one barrier per tile ----
    ISSUE_T(0)
    for (int kt = 0; kt < 16; ++kt) {       // full tiles: X part, 4 outputs
        VM0; MEMF; BAR; MEMF;
        ISSUE_T(kt + 1)
        MEMF;
        BODY(kt, 4)
    }
    for (int kt = 16; kt < 32; ++kt) {      // tail tiles: S part, Zc/Zw only
        VM0; MEMF; BAR; MEMF;
        if (kt + 1 < 32) ISSUE_T(kt + 1)
        MEMF;
        BODY(kt, 2)
    }

#undef ISSUE_T
#undef BODY

    // ---- fused epilogue (bf16 Xb/Sb reads) ----
    // C/D frag layout (m89/m91): col = lane&15, row = (lane>>4)*4 + reg
    const int col = ncol0 + wn * 16 + l15;
    const float vzc = bzc[col], vzw = bzw[col], vit = bit_[col], vh = bh[col];
    #pragma unroll
    for (int mf = 0; mf < 8; ++mf) {
        #pragma unroll
        for (int j = 0; j < 4; ++j) {
            const int row = arow0 + mf * 16 + (lane >> 4) * 4 + j;
            const size_t off = (size_t)row * DDIM + col;
            const float zw = sigf(acc[1][mf][j] + vzw);
            const float hh = sigf(acc[3][mf][j] + vh);
            out[off] = sigf((1.0f - zw) * (float)Sb[off] + zw * hh
                            + (float)Xb[off]);                       // S_new
            out[(size_t)BROWS * DDIM + off] =
                (acc[0][mf][j] + vzc) + (acc[2][mf][j] + vit);       // C_new
        }
    }
}

// ===================== fallback (ws too small): R4 path =====================
__global__ __launch_bounds__(256)
void petnn_cvtw(const float* __restrict__ Wzw, const float* __restrict__ Wh,
                const float* __restrict__ Wzc, const float* __restrict__ Wit,
                __bf16* __restrict__ wb)
{
    const int i = blockIdx.x * 256 + threadIdx.x;
    const float* src; size_t dst;
    if (i < 131072)      { src = Wzw + (size_t)i * 4;  dst = (size_t)i * 4; }
    else if (i < 196608) { const int j = i - 131072;
                           src = Wh + (size_t)(j >> 7) * 1024 + (j & 127) * 4;
                           dst = 524288 + (size_t)j * 4; }
    else if (i < 327680) { const int j = i - 196608;
                           src = Wzc + (size_t)j * 4;  dst = 786432 + (size_t)j * 4; }
    else                 { const int j = i - 327680;
                           src = Wit + (size_t)j * 4;  dst = 1310720 + (size_t)j * 4; }
    *(bf16x4*)(wb + dst) = cvt4(*(const f32x4*)src);
}

__global__ __launch_bounds__(512, 4)
void petnn_fused(const float* __restrict__ X,   const float* __restrict__ S,
                 const __bf16* __restrict__ wb,
                 const float* __restrict__ bzw, const float* __restrict__ bh,
                 const float* __restrict__ bzc, const float* __restrict__ bit_,
                 float* __restrict__ out)
{
    __shared__ __align__(16) __bf16 sA[128 * 64];
    __shared__ __align__(16) __bf16 sB[2 * 2 * 64 * 64];

    const int tid = threadIdx.x;
    const int bid = blockIdx.x;
    const int orig = (bid & 7) * 256 + (bid >> 3);
    const int fam  = orig & 1;
    const int nblk = (orig >> 1) & 7;
    const int mblk = orig >> 4;
    const int lane = tid & 63, wid = tid >> 6;
    const int wm = wid >> 2, wn = wid & 3;
    const int arow0 = mblk * 128, ncol0 = nblk * 64;
    const int srow = tid >> 4, skq = (tid & 15) << 2;
    const int bn = tid >> 3;
    const int bks = ((tid & 7) ^ (bn & 7)) << 3;
    const __bf16* wP = wb + (size_t)fam * 786432 + (size_t)(ncol0 + bn) * 1024 + bks;
    const __bf16* wQ = wb + (size_t)fam * 786432 + 524288 + (size_t)(ncol0 + bn) * 512 + bks;
    __bf16* ldsB = sB + tid * 8;

    f32x4 aP[4] = {}, aQ[4] = {};
    f32x4 ra[4];

    glds16(wP, ldsB);
    glds16(wQ, ldsB + 4096);
    #pragma unroll
    for (int p = 0; p < 4; ++p)
        ra[p] = *(const f32x4*)(X + (size_t)(arow0 + p * 32 + srow) * DDIM + skq);
    glds16(wP + 64, ldsB + 8192);
    glds16(wQ + 64, ldsB + 8192 + 4096);

    for (int kt = 0; kt < 16; ++kt) {
        const bool full = kt < 8;
        #pragma unroll
        for (int p = 0; p < 4; ++p) {
            const int r = p * 32 + srow;
            *(bf16x4*)(sA + r * 64 + (skq ^ ((r & 7) * 8))) = cvt4(ra[p]);
        }
        if (kt + 1 < 16) {
            const float* asrc = (kt + 1 < 8) ? X : S;
            const int kga = ((kt + 1) & 7) * 64 + skq;
            #pragma unroll
            for (int p = 0; p < 4; ++p)
                ra[p] = *(const f32x4*)(asrc + (size_t)(arow0 + p * 32 + srow) * DDIM + kga);
        }
        asm volatile("s_waitcnt lgkmcnt(0)" ::: "memory");
        __builtin_amdgcn_s_barrier();

        const __bf16* bb = sB + (kt & 1) * 8192;
        #pragma unroll
        for (int kk = 0; kk < 2; ++kk) {
            const int kbe = kk * 32 + (lane >> 4) * 8;
            bf16x8 af[4];
            #pragma unroll
            for (int mf = 0; mf < 4; ++mf) {
                const int r = wm * 64 + mf * 16 + (lane & 15);
                af[mf] = *(const bf16x8*)(sA + r * 64 + (kbe ^ ((r & 7) * 8)));
            }
            const int nr = wn * 16 + (lane & 15);
            const int sx = nr * 64 + (kbe ^ ((nr & 7) * 8));
            const bf16x8 bP = *(const bf16x8*)(bb + sx);
            #pragma unroll
            for (int mf = 0; mf < 4; ++mf)
                aP[mf] = __builtin_amdgcn_mfma_f32_16x16x32_bf16(af[mf], bP, aP[mf], 0, 0, 0);
            if (full) {
                const bf16x8 bQ = *(const bf16x8*)(bb + 4096 + sx);
                #pragma unroll
                for (int mf = 0; mf < 4; ++mf)
                    aQ[mf] = __builtin_amdgcn_mfma_f32_16x16x32_bf16(af[mf], bQ, aQ[mf], 0, 0, 0);
            }
        }

        if (kt + 1 < 16) {
            asm volatile("" ::: "memory");
            __builtin_amdgcn_s_barrier();
            asm volatile("" ::: "memory");
            if (kt + 2 < 16) {
                __bf16* bd = sB + (kt & 1) * 8192 + tid * 8;
                glds16(wP + (size_t)(kt + 2) * 64, bd);
                if (kt + 2 < 8) glds16(wQ + (size_t)(kt + 2) * 64, bd + 4096);
            }
        }
    }

    const int col  = ncol0 + wn * 16 + (lane & 15);
    const int rowb = arow0 + wm * 64;
    if (fam == 0) {
        const float vzw = bzw[col], vh = bh[col];
        #pragma unroll
        for (int mf = 0; mf < 4; ++mf) {
            #pragma unroll
            for (int j = 0; j < 4; ++j) {
                const int row = rowb + mf * 16 + ((lane >> 4) << 2) + j;
                const size_t off = (size_t)row * DDIM + col;
                const float zw = sigf(aP[mf][j] + vzw);
                const float hh = sigf(aQ[mf][j] + vh);
                out[off] = sigf((1.0f - zw) * S[off] + zw * hh + X[off]);
            }
        }
    } else {
        const float vzc = bzc[col], vit = bit_[col];
        #pragma unroll
        for (int mf = 0; mf < 4; ++mf) {
            #pragma unroll
            for (int j = 0; j < 4; ++j) {
                const int row = rowb + mf * 16 + ((lane >> 4) << 2) + j;
                const size_t off = (size_t)row * DDIM + col;
                out[(size_t)BROWS * DDIM + off] =
                    (aP[mf][j] + vzc) + (aQ[mf][j] + vit);
            }
        }
    }
}

__global__ void petnn_zeroT(float* __restrict__ t) {
    t[blockIdx.x * 256 + threadIdx.x] = 0.0f;
}

extern "C" void kernel_launch(void* const* d_in, const int* in_sizes, int n_in,
                              void* d_out, int out_size, void* d_ws, size_t ws_size,
                              hipStream_t stream) {
    (void)in_sizes; (void)n_in; (void)out_size;
    const float* X    = (const float*)d_in[0];
    const float* S    = (const float*)d_in[1];
    const float* Wzc  = (const float*)d_in[6];
    const float* bzc  = (const float*)d_in[7];
    const float* Wzw  = (const float*)d_in[8];
    const float* bzw  = (const float*)d_in[9];
    const float* Wit  = (const float*)d_in[10];
    const float* bit_ = (const float*)d_in[11];
    const float* Wh   = (const float*)d_in[14];
    const float* bh   = (const float*)d_in[15];
    float* out = (float*)d_out;

    if (ws_size >= 36700160u) {
        __bf16* ws = (__bf16*)d_ws;
        const __bf16* Xb = ws;
        const __bf16* Sb = ws + 8388608;
        const __bf16* wb = ws + 16777216;
        petnn_cvt<<<dim3(17936), dim3(256), 0, stream>>>(
            X, S, Wzc, Wzw, Wit, Wh, ws, out + 2 * (size_t)BROWS * DDIM);
        petnn_fusedE<<<dim3(1024), dim3(256), 0, stream>>>(
            Xb, Sb, wb, bzc, bzw, bit_, bh, out);
    } else {
        __bf16* wb = (__bf16*)d_ws;
        petnn_cvtw<<<dim3(1536), dim3(256), 0, stream>>>(Wzw, Wh, Wzc, Wit, wb);
        petnn_fused<<<dim3(2048), dim3(512), 0, stream>>>(
            X, S, wb, bzw, bh, bzc, bit_, out);
        petnn_zeroT<<<dim3(64), dim3(256), 0, stream>>>(out + 2 * (size_t)BROWS * DDIM);
    }
}